// Round 7
// baseline (858.303 us; speedup 1.0000x reference)
//
#include <hip/hip_runtime.h>
#include <math.h>

// Problem constants: B=1048576, DX=32, DS=16, H=128, K=64, NSN=4
#define DXc 32
#define DSc 16
#define Hc  128
#define Kc  64
#define NSNc 4

// ===== ROUND 7: A/B DIAGNOSTIC BUILD (sacrificial) =====
// Two dispatches, each REPS=3 with rotated row assignment so every rep is
// cold-ish in L3 (rotation = 5n/8, breaks block-local reuse seen in R6).
// Each dispatch lasts ~3x157us -> outranks the ~320us fill kernels -> we
// finally get per-dispatch counters for BOTH access-pattern variants:
//   kernel1: exact R1 per-thread row-major body (champion, 157.7us)
//   kernel2: same arithmetic, hidden staged via wave-private XOR-swizzled
//            LDS with fully-coalesced chunk loads (1 request per 128B line),
//            NO barriers (same-wave LDS RAW -> lgkmcnt only).
// Both write correct out[] each rep (idempotent, last write wins).
#define REPS 3

// --------------------------------------------------------------------------
// Shared table setup (identical in both kernels)
#define TABLE_SETUP()                                                         \
    __shared__ float sWc[Kc][DSc + 1];                                        \
    __shared__ float sbc[Kc];                                                 \
    __shared__ float sc2[Kc];                                                 \
    {                                                                         \
        const int tid_ = threadIdx.x;                                         \
        for (int e = tid_; e < Kc * DSc; e += 256) {                          \
            const int c = e >> 4;                                             \
            const int j = e & 15;                                             \
            float acc = 0.f;                                                  \
            _Pragma("unroll")                                                 \
            for (int nn = 0; nn < NSNc; ++nn)                                 \
                acc = fmaf(rsw[c * NSNc + nn], W_sn[(nn * Kc + c) * DSc + j], acc); \
            sWc[c][j] = acc;                                                  \
        }                                                                     \
        if (tid_ < Kc) {                                                      \
            const int c = tid_;                                               \
            float accb = 0.f;                                                 \
            _Pragma("unroll")                                                 \
            for (int nn = 0; nn < NSNc; ++nn)                                 \
                accb = fmaf(rsw[c * NSNc + nn], b_sn[nn * Kc + c], accb);     \
            sbc[c] = accb;                                                    \
            float c2 = 0.f;                                                   \
            _Pragma("unroll")                                                 \
            for (int d = 0; d < DXc; ++d) {                                   \
                const float cv = centers[c * DXc + d];                        \
                c2 = fmaf(cv, cv, c2);                                        \
            }                                                                 \
            sc2[c] = c2;                                                      \
        }                                                                     \
        __syncthreads();                                                      \
    }

// Exact R1 dist/argmin (single sequential accumulator — validated ordering).
#define DIST_ARGMIN(xr, bestk)                                                \
    int bestk = 0;                                                            \
    {                                                                         \
        float bestd = INFINITY;                                               \
        _Pragma("unroll 2")                                                   \
        for (int k = 0; k < Kc; ++k) {                                        \
            float dot = 0.f;                                                  \
            _Pragma("unroll")                                                 \
            for (int d = 0; d < DXc; ++d)                                     \
                dot = fmaf(xr[d], centers[k * DXc + d], dot);                 \
            const float dist = fmaf(-2.0f, dot, sc2[k]);                      \
            if (dist < bestd) { bestd = dist; bestk = k; }                    \
        }                                                                     \
    }

// ============================ Kernel 1 =====================================
// R1 per-thread row-major body, REPS rotated sweeps.
__global__ __launch_bounds__(256, 4) void k_rowmajor(
    const float* __restrict__ x,
    const float* __restrict__ s,
    const float* __restrict__ hidden,
    const float* __restrict__ naive_pred,
    const float* __restrict__ centers,
    const float* __restrict__ W_tune,
    const float* __restrict__ b_tune,
    const float* __restrict__ W_sn,
    const float* __restrict__ b_sn,
    const float* __restrict__ rsw,
    float* __restrict__ out,
    int n, long long rot)
{
    TABLE_SETUP();

    const size_t b0 = (size_t)blockIdx.x * 256 + threadIdx.x;
    if (b0 >= (size_t)n) return;

    for (int rep = 0; rep < REPS; ++rep) {
        asm volatile("" ::: "memory");
        const size_t b = (b0 + (size_t)rep * (size_t)rot) % (size_t)n;

        float xr[DXc];
        {
            const float4* x4 = reinterpret_cast<const float4*>(x + b * DXc);
#pragma unroll
            for (int i = 0; i < DXc / 4; ++i) {
                const float4 v = x4[i];
                xr[i * 4 + 0] = v.x; xr[i * 4 + 1] = v.y;
                xr[i * 4 + 2] = v.z; xr[i * 4 + 3] = v.w;
            }
        }

        float hacc = 0.f;
        {
            const float4* h4 = reinterpret_cast<const float4*>(hidden + b * Hc);
#pragma unroll 8
            for (int i = 0; i < Hc / 4; ++i) {
                const float4 v = h4[i];
                hacc = fmaf(v.x, W_tune[i * 4 + 0], hacc);
                hacc = fmaf(v.y, W_tune[i * 4 + 1], hacc);
                hacc = fmaf(v.z, W_tune[i * 4 + 2], hacc);
                hacc = fmaf(v.w, W_tune[i * 4 + 3], hacc);
            }
        }
        const float z = hacc + b_tune[0];
        const float x_tune = 1.0f / (1.0f + __expf(-z));

        DIST_ARGMIN(xr, bestk);

        float snacc = sbc[bestk];
        {
            const float4* s4 = reinterpret_cast<const float4*>(s + b * DSc);
#pragma unroll
            for (int i = 0; i < DSc / 4; ++i) {
                const float4 v = s4[i];
                snacc = fmaf(v.x, sWc[bestk][i * 4 + 0], snacc);
                snacc = fmaf(v.y, sWc[bestk][i * 4 + 1], snacc);
                snacc = fmaf(v.z, sWc[bestk][i * 4 + 2], snacc);
                snacc = fmaf(v.w, sWc[bestk][i * 4 + 3], snacc);
            }
        }
        const float np_ = naive_pred[b];
        out[b] = snacc + x_tune * (np_ - snacc);
    }
}

// ============================ Kernel 2 =====================================
// Same arithmetic; hidden staged per-wave via XOR-swizzled LDS, coalesced
// chunk loads (8 full 128B lines per instruction), barrier-free.
__global__ __launch_bounds__(256, 4) void k_staged(
    const float* __restrict__ x,
    const float* __restrict__ s,
    const float* __restrict__ hidden,
    const float* __restrict__ naive_pred,
    const float* __restrict__ centers,
    const float* __restrict__ W_tune,
    const float* __restrict__ b_tune,
    const float* __restrict__ W_sn,
    const float* __restrict__ b_sn,
    const float* __restrict__ rsw,
    float* __restrict__ out,
    int n, long long rot)
{
    TABLE_SETUP();

    // Per-wave chunk buffer: [wave][row 0..63][8 float4, XOR-swizzled].
    // Row stride 128B; col q stored at q^(row&7) -> reads/writes spread over
    // all 32 banks (8 dwords/bank minimum = conflict-free).
    __shared__ __align__(16) float hbuf[4][64][32];

    const int tid  = threadIdx.x;
    const int lane = tid & 63;
    const int w    = tid >> 6;

    const size_t b0 = (size_t)blockIdx.x * 256 + tid;
    if (b0 >= (size_t)n) return;

    const size_t wb0 = (size_t)blockIdx.x * 256 + (tid & ~63);

    for (int rep = 0; rep < REPS; ++rep) {
        asm volatile("" ::: "memory");
        const size_t wrowbase = (wb0 + (size_t)rep * (size_t)rot) % (size_t)n;
        const size_t b = (b0 + (size_t)rep * (size_t)rot) % (size_t)n;

        float xr[DXc];
        {
            const float4* x4 = reinterpret_cast<const float4*>(x + b * DXc);
#pragma unroll
            for (int i = 0; i < DXc / 4; ++i) {
                const float4 v = x4[i];
                xr[i * 4 + 0] = v.x; xr[i * 4 + 1] = v.y;
                xr[i * 4 + 2] = v.z; xr[i * 4 + 3] = v.w;
            }
        }

        float hacc = 0.f;
        if (wrowbase + 64 <= (size_t)n) {
            // Fast path: wave owns rows [wrowbase, wrowbase+64).
            const float4* h4 = reinterpret_cast<const float4*>(hidden);
            for (int c = 0; c < 4; ++c) {
                // Stage chunk c: instr i covers 8 rows x 128B contiguous segs.
#pragma unroll
                for (int i = 0; i < 8; ++i) {
                    const int sidx = i * 64 + lane;        // [0,512)
                    const int rr = sidx >> 3;              // row in wave
                    const int q  = sidx & 7;               // float4 col in chunk
                    const float4 v = h4[(wrowbase + rr) * (Hc / 4) + c * 8 + q];
                    *reinterpret_cast<float4*>(&hbuf[w][rr][(q ^ (rr & 7)) * 4]) = v;
                }
                // Same-wave LDS RAW -> compiler emits lgkmcnt wait; no barrier.
#pragma unroll
                for (int q = 0; q < 8; ++q) {
                    const float4 v = *reinterpret_cast<const float4*>(
                        &hbuf[w][lane][(q ^ (lane & 7)) * 4]);
                    const int wbase = c * 32 + q * 4;
                    hacc = fmaf(v.x, W_tune[wbase + 0], hacc);
                    hacc = fmaf(v.y, W_tune[wbase + 1], hacc);
                    hacc = fmaf(v.z, W_tune[wbase + 2], hacc);
                    hacc = fmaf(v.w, W_tune[wbase + 3], hacc);
                }
            }
        } else {
            // Tail fallback: direct per-thread reads (same accumulation order).
            const float4* h4 = reinterpret_cast<const float4*>(hidden + b * Hc);
#pragma unroll 8
            for (int i = 0; i < Hc / 4; ++i) {
                const float4 v = h4[i];
                hacc = fmaf(v.x, W_tune[i * 4 + 0], hacc);
                hacc = fmaf(v.y, W_tune[i * 4 + 1], hacc);
                hacc = fmaf(v.z, W_tune[i * 4 + 2], hacc);
                hacc = fmaf(v.w, W_tune[i * 4 + 3], hacc);
            }
        }
        const float z = hacc + b_tune[0];
        const float x_tune = 1.0f / (1.0f + __expf(-z));

        DIST_ARGMIN(xr, bestk);

        float snacc = sbc[bestk];
        {
            const float4* s4 = reinterpret_cast<const float4*>(s + b * DSc);
#pragma unroll
            for (int i = 0; i < DSc / 4; ++i) {
                const float4 v = s4[i];
                snacc = fmaf(v.x, sWc[bestk][i * 4 + 0], snacc);
                snacc = fmaf(v.y, sWc[bestk][i * 4 + 1], snacc);
                snacc = fmaf(v.z, sWc[bestk][i * 4 + 2], snacc);
                snacc = fmaf(v.w, sWc[bestk][i * 4 + 3], snacc);
            }
        }
        const float np_ = naive_pred[b];
        out[b] = snacc + x_tune * (np_ - snacc);
    }
}

extern "C" void kernel_launch(void* const* d_in, const int* in_sizes, int n_in,
                              void* d_out, int out_size, void* d_ws, size_t ws_size,
                              hipStream_t stream) {
    const float* x          = (const float*)d_in[0];
    const float* s          = (const float*)d_in[1];
    const float* hidden     = (const float*)d_in[2];
    const float* naive_pred = (const float*)d_in[3];
    const float* centers    = (const float*)d_in[4];
    const float* W_tune     = (const float*)d_in[5];
    const float* b_tune     = (const float*)d_in[6];
    const float* W_sn       = (const float*)d_in[7];
    const float* b_sn       = (const float*)d_in[8];
    const float* rsw        = (const float*)d_in[9];
    float* out = (float*)d_out;

    const int n = in_sizes[3];  // B
    // Rotation: multiple of 64, ~5n/8 — pushes each rep's rows out of the
    // L3-resident cohort of the previous rep.
    long long rot = (((long long)n * 5) / 8) & ~63LL;
    if (rot <= 0) rot = 64;

    const int blocks = (n + 255) / 256;
    k_rowmajor<<<blocks, 256, 0, stream>>>(x, s, hidden, naive_pred, centers,
                                           W_tune, b_tune, W_sn, b_sn, rsw,
                                           out, n, rot);
    k_staged<<<blocks, 256, 0, stream>>>(x, s, hidden, naive_pred, centers,
                                         W_tune, b_tune, W_sn, b_sn, rsw,
                                         out, n, rot);
}

// Round 8
// 199.552 us; speedup vs baseline: 4.3011x; 4.3011x over previous
//
#include <hip/hip_runtime.h>
#include <math.h>

// Problem constants: B=1048576, DX=32, DS=16, H=128, K=64, NSN=4
#define DXc 32
#define DSc 16
#define Hc  128
#define Kc  64
#define NSNc 4

// ===== ROUND 8: full-row up-front load stream =====
// R7 counters: nothing saturated (hbm 29%, VALU 44%, occ 59%), VGPR=40 ->
// only ~5 loads in flight; per-sweep time ~= mem_time + compute_time (serial
// convoy). Fix: issue ALL 45 row loads (x8 + hidden32 + s4 + naive1) before
// any consuming FMA (sched_barrier(0) pins the order), consume in issue
// order so compiler emits fine-grained vmcnt(N) waits -> compute overlaps
// the stream tail. ~200 VGPR -> launch_bounds(256,2), 8 waves/CU (plenty:
// latency-hiding needs ~9KB in flight/CU; fills sustain 6.7TB/s at 10% occ).
// Arithmetic byte-identical to the validated R1 champion.
__global__ __launch_bounds__(256, 2) void snclust_fused(
    const float* __restrict__ x,
    const float* __restrict__ s,
    const float* __restrict__ hidden,
    const float* __restrict__ naive_pred,
    const float* __restrict__ centers,
    const float* __restrict__ W_tune,
    const float* __restrict__ b_tune,
    const float* __restrict__ W_sn,
    const float* __restrict__ b_sn,
    const float* __restrict__ rsw,
    float* __restrict__ out,
    int n)
{
    // Combined SN weights: Wc[c][j] = sum_n rsw[c,n] * W_sn[n,c,j]
    //                      bc[c]    = sum_n rsw[c,n] * b_sn[n,c]
    __shared__ float sWc[Kc][DSc + 1];
    __shared__ float sbc[Kc];
    __shared__ float sc2[Kc];

    const int tid = threadIdx.x;

    for (int e = tid; e < Kc * DSc; e += 256) {
        const int c = e >> 4;
        const int j = e & 15;
        float acc = 0.f;
#pragma unroll
        for (int nn = 0; nn < NSNc; ++nn)
            acc = fmaf(rsw[c * NSNc + nn], W_sn[(nn * Kc + c) * DSc + j], acc);
        sWc[c][j] = acc;
    }
    if (tid < Kc) {
        const int c = tid;
        float accb = 0.f;
#pragma unroll
        for (int nn = 0; nn < NSNc; ++nn)
            accb = fmaf(rsw[c * NSNc + nn], b_sn[nn * Kc + c], accb);
        sbc[c] = accb;
        float c2 = 0.f;
#pragma unroll
        for (int d = 0; d < DXc; ++d) {
            const float cv = centers[c * DXc + d];
            c2 = fmaf(cv, cv, c2);
        }
        sc2[c] = c2;
    }
    __syncthreads();

    const size_t b = (size_t)blockIdx.x * 256 + tid;
    if (b >= (size_t)n) return;

    // ---------- Phase 1: issue the ENTIRE row stream (45 loads) ----------
    float4 xv[8];
    float4 hv[32];
    float4 sv[4];
    float np_;
    {
        const float4* x4 = reinterpret_cast<const float4*>(x + b * DXc);
#pragma unroll
        for (int i = 0; i < 8; ++i) xv[i] = x4[i];

        const float4* h4 = reinterpret_cast<const float4*>(hidden + b * Hc);
#pragma unroll
        for (int i = 0; i < 32; ++i) hv[i] = h4[i];

        const float4* s4 = reinterpret_cast<const float4*>(s + b * DSc);
#pragma unroll
        for (int i = 0; i < 4; ++i) sv[i] = s4[i];

        np_ = naive_pred[b];
    }
    // Pin: no compute scheduled above this point, no loads below it.
    __builtin_amdgcn_sched_barrier(0);

    // ---------- Phase 2: consume in issue order (bit-exact R1 math) ----------
    // hidden dot: ascending i, x,y,z,w — identical accumulation order to R1.
    float hacc = 0.f;
#pragma unroll
    for (int i = 0; i < 32; ++i) {
        const float4 v = hv[i];
        hacc = fmaf(v.x, W_tune[i * 4 + 0], hacc);
        hacc = fmaf(v.y, W_tune[i * 4 + 1], hacc);
        hacc = fmaf(v.z, W_tune[i * 4 + 2], hacc);
        hacc = fmaf(v.w, W_tune[i * 4 + 3], hacc);
    }
    const float z = hacc + b_tune[0];
    const float x_tune = 1.0f / (1.0f + __expf(-z));

    // Unpack x (register renaming only — values identical).
    float xr[DXc];
#pragma unroll
    for (int i = 0; i < 8; ++i) {
        xr[i * 4 + 0] = xv[i].x; xr[i * 4 + 1] = xv[i].y;
        xr[i * 4 + 2] = xv[i].z; xr[i * 4 + 3] = xv[i].w;
    }

    // argmin: EXACT R1 arithmetic — single sequential accumulator,
    // ascending d, ascending k, strict <. (Rounding-sensitive on near-ties.)
    int bestk = 0;
    float bestd = INFINITY;
#pragma unroll 2
    for (int k = 0; k < Kc; ++k) {
        float dot = 0.f;
#pragma unroll
        for (int d = 0; d < DXc; ++d)
            dot = fmaf(xr[d], centers[k * DXc + d], dot);
        const float dist = fmaf(-2.0f, dot, sc2[k]);
        if (dist < bestd) { bestd = dist; bestk = k; }
    }

    // combined SN dot: EXACT R1 order, from prefetched sv.
    float snacc = sbc[bestk];
#pragma unroll
    for (int i = 0; i < DSc / 4; ++i) {
        const float4 v = sv[i];
        snacc = fmaf(v.x, sWc[bestk][i * 4 + 0], snacc);
        snacc = fmaf(v.y, sWc[bestk][i * 4 + 1], snacc);
        snacc = fmaf(v.z, sWc[bestk][i * 4 + 2], snacc);
        snacc = fmaf(v.w, sWc[bestk][i * 4 + 3], snacc);
    }

    out[b] = snacc + x_tune * (np_ - snacc);
}

extern "C" void kernel_launch(void* const* d_in, const int* in_sizes, int n_in,
                              void* d_out, int out_size, void* d_ws, size_t ws_size,
                              hipStream_t stream) {
    const float* x          = (const float*)d_in[0];
    const float* s          = (const float*)d_in[1];
    const float* hidden     = (const float*)d_in[2];
    const float* naive_pred = (const float*)d_in[3];
    const float* centers    = (const float*)d_in[4];
    const float* W_tune     = (const float*)d_in[5];
    const float* b_tune     = (const float*)d_in[6];
    const float* W_sn       = (const float*)d_in[7];
    const float* b_sn       = (const float*)d_in[8];
    const float* rsw        = (const float*)d_in[9];
    float* out = (float*)d_out;

    const int n = in_sizes[3];  // B
    const int blocks = (n + 255) / 256;
    snclust_fused<<<blocks, 256, 0, stream>>>(x, s, hidden, naive_pred, centers,
                                              W_tune, b_tune, W_sn, b_sn, rsw,
                                              out, n);
}